// Round 9
// baseline (259.531 us; speedup 1.0000x reference)
//
#include <hip/hip_runtime.h>
#include <hip/hip_bf16.h>

// Problem constants
#define NTOT 262144
#define LDIM 1024
#define DDIM 128
#define FDIM 32
#define NBAGS 256

typedef __attribute__((ext_vector_type(8))) short bf16x8;
typedef __attribute__((ext_vector_type(4))) float f32x4;

__device__ __forceinline__ unsigned short f2b(float f) {
    __hip_bfloat16 h = __float2bfloat16(f);   // RNE
    return __builtin_bit_cast(unsigned short, h);
}
__device__ __forceinline__ float b2f(unsigned short u) {
    union { float f; unsigned int i; } c;
    c.i = ((unsigned int)u) << 16;
    return c.f;
}

// ---------------------------------------------------------------------------
// K0: (a) W1 [1024][128] fp32 -> w1t2: kt-tiled, PRE-SWIZZLED bf16 layout:
//     element (col,k): kt=k>>6, ko=k&63, cc=ko>>3, kr=ko&7 ->
//     w1t2[kt*8192 + col*64 + (cc^(col&7))*8 + kr]. GEMM stages with a pure
//     linear copy; the MFMA read-side XOR undoes the pre-swizzle.
//     (b) Wt/Ws -> wtT/wsT [32][128] bf16.  (c) zero Mraw/dden.
// ---------------------------------------------------------------------------
__global__ void k_prep(const float* __restrict__ W1, const float* __restrict__ Wt,
                       const float* __restrict__ Ws,
                       ushort* __restrict__ w1t2, ushort* __restrict__ wtT,
                       ushort* __restrict__ wsT,
                       float* __restrict__ Mraw, float* __restrict__ dden) {
    int gid = blockIdx.x * 256 + threadIdx.x;          // 512*256 = 131072 threads
    if (gid < LDIM * DDIM) {
        int col = gid & 127, k = gid >> 7;             // W1 row-major: gid = k*128+col
        int kt = k >> 6, ko = k & 63;
        int cc = ko >> 3, kr = ko & 7;
        w1t2[kt * 8192 + col * 64 + (cc ^ (col & 7)) * 8 + kr] = f2b(W1[gid]);
    }
    if (gid < DDIM * FDIM) {                           // 4096
        int f = gid & 31, d = gid >> 5;                // Wt row-major: gid = d*32+f
        wtT[f * 128 + d] = f2b(Wt[gid]);
        wsT[f * 128 + d] = f2b(Ws[gid]);
    }
    if (gid < NBAGS * DDIM) Mraw[gid] = 0.0f;
    if (gid < NBAGS) dden[gid] = 0.0f;
}

// ---------------------------------------------------------------------------
// K1: H = relu(x@W1+b1) (stays in LDS); a = (tanh(HWt+bt)*sigmoid(HWs+bs))@Wa+ba
// w = exp(a) (|a| <= ~5.7, no max needed); per-bag partials into Mraw/den.
// 512 threads, 128x128 tile, BK=64, 8 waves (4x2), wave tile 32x64.
// DOUBLE-BUFFERED LDS (one barrier/kt) + TWO-DEEP register prefetch:
//   stage(kt)->buf[p] [loads issued at kt-2] -> barrier -> issue(kt+2) -> MFMA(kt)
// Safety: stage(kt+2) writes buf[p] only after barrier(kt+1), which each wave
// passes after its MFMA(kt) reads of buf[p] (program order) -> race-free.
// vmcnt window ~2 iterations; single barrier lets waves drift (de-burst).
// ---------------------------------------------------------------------------
__global__ __launch_bounds__(512, 4) void k_fused_gemm(
    const float* __restrict__ x, const ushort* __restrict__ w1t2,
    const ushort* __restrict__ wtT, const ushort* __restrict__ wsT,
    const float* __restrict__ b1,
    const float* __restrict__ bt, const float* __restrict__ bs,
    const float* __restrict__ Wa, const float* __restrict__ ba,
    const int* __restrict__ idxs,
    float* __restrict__ Mraw, float* __restrict__ dden)
{
    __shared__ __align__(16) ushort sA2[2][8192];  // 2 x 16 KB A tiles; later sH (32 KB)
    __shared__ __align__(16) ushort sB2[2][8192];  // 2 x 16 KB B tiles
    __shared__ float sb1[128];
    __shared__ float sbt[32], sbs[32], sWa[32];
    __shared__ float sw[128];                      // per-row softmax weight
    __shared__ int   sbag[128];                    // per-row bag id

    const int t    = threadIdx.x;
    const int lane = t & 63;
    const int wave = t >> 6;                       // 0..7
    const int wr   = wave >> 1, wc = wave & 1;     // wave tile: rows wr*32, cols wc*64
    const int lq   = lane >> 4, lr = lane & 15;
    const int row0 = blockIdx.x * 128;

    if (t < 128) { sb1[t] = b1[t]; sbag[t] = idxs[row0 + t]; }
    if (t < 32)  { sbt[t] = bt[t]; sbs[t] = bs[t]; sWa[t] = Wa[t]; }
    const float ba0 = ba[0];

    f32x4 acc[2][4];
#pragma unroll
    for (int m = 0; m < 2; ++m)
#pragma unroll
        for (int n = 0; n < 4; ++n) acc[m][n] = 0;

    // ---- staging geometry ----
    // A: j=0..3, row = (t>>4) + 32j, colchunk = t&15 (16B of fp32)
    const int arow  = t >> 4;                  // 0..31
    const int acol4 = (t & 15) * 4;            // fp32 col 0..60
    const float* xb = x + (size_t)(row0 + arow) * LDIM + acol4;
    const int a_base = (((acol4 >> 3) ^ (arow & 7)) << 4) + (acol4 & 7) * 2;
    // B: linear copy, chunk c = t + 512*jj -> 16 B at sB + c*16
    const ushort* bb = w1t2 + t * 8;

    // prologue: issue loads for kt=0 (slot 0) and kt=1 (slot 1)
    float4 av[2][4];
    bf16x8 bv[2][2];
#pragma unroll
    for (int j = 0; j < 4; ++j) av[0][j] = *(const float4*)(xb + j * (32 * LDIM));
#pragma unroll
    for (int jj = 0; jj < 2; ++jj) bv[0][jj] = *(const bf16x8*)(bb + jj * 4096);
#pragma unroll
    for (int j = 0; j < 4; ++j) av[1][j] = *(const float4*)(xb + 64 + j * (32 * LDIM));
#pragma unroll
    for (int jj = 0; jj < 2; ++jj) bv[1][jj] = *(const bf16x8*)(bb + 8192 + jj * 4096);

    for (int kt = 0; kt < 16; ++kt) {
        const int p = kt & 1;
        char* sA = (char*)sA2[p];
        char* sB = (char*)sB2[p];

        // stage registers (issued at kt-2) -> LDS buffer p
#pragma unroll
        for (int j = 0; j < 4; ++j) {
            float4 f = av[p][j];
            uint2 pk;
            pk.x = (unsigned)f2b(f.x) | ((unsigned)f2b(f.y) << 16);
            pk.y = (unsigned)f2b(f.z) | ((unsigned)f2b(f.w) << 16);
            *(uint2*)(sA + (arow + 32 * j) * 128 + a_base) = pk;
        }
#pragma unroll
        for (int jj = 0; jj < 2; ++jj)
            *(bf16x8*)(sB + t * 16 + jj * 8192) = bv[p][jj];

        __syncthreads();   // single barrier per kt (dbuf makes it sufficient)

        // issue loads for kt+2 into the register slot just freed
        if (kt < 14) {
            const float* xk = xb + (kt + 2) * 64;
#pragma unroll
            for (int j = 0; j < 4; ++j) av[p][j] = *(const float4*)(xk + j * (32 * LDIM));
            const ushort* bk = bb + (kt + 2) * 8192;
#pragma unroll
            for (int jj = 0; jj < 2; ++jj) bv[p][jj] = *(const bf16x8*)(bk + jj * 4096);
        }

#pragma unroll
        for (int kk = 0; kk < 2; ++kk) {
            bf16x8 aF[2], bF[4];
#pragma unroll
            for (int m = 0; m < 2; ++m) {
                int ra = wr * 32 + m * 16 + lr;    // A: row = lane%16
                aF[m] = *(const bf16x8*)(sA + ra * 128 + (((kk * 4 + lq) ^ (ra & 7)) << 4));
            }
#pragma unroll
            for (int n = 0; n < 4; ++n) {
                int cb = wc * 64 + n * 16 + lr;    // B: col = lane%16
                bF[n] = *(const bf16x8*)(sB + cb * 128 + (((kk * 4 + lq) ^ (cb & 7)) << 4));
            }
#pragma unroll
            for (int m = 0; m < 2; ++m)
#pragma unroll
                for (int n = 0; n < 4; ++n)
                    acc[m][n] = __builtin_amdgcn_mfma_f32_16x16x32_bf16(aF[m], bF[n], acc[m][n], 0, 0, 0);
        }
    }
    __syncthreads();   // K-loop LDS dead; reuse sA2 (32 KB) as sH

    // epilogue: bias + relu, bf16, into swizzled sH [128 rows][256 B], slot ^= row&15
    char* sH = (char*)sA2;
#pragma unroll
    for (int m = 0; m < 2; ++m) {
#pragma unroll
        for (int n = 0; n < 4; ++n) {
            const int colg = wc * 64 + n * 16 + lr;          // C/D: col = lane&15
            const float bias = sb1[colg];
#pragma unroll
            for (int r = 0; r < 4; ++r) {
                const int rowl = wr * 32 + m * 16 + lq * 4 + r; // C/D: row = (lane>>4)*4+reg
                float h = acc[m][n][r] + bias;
                h = fmaxf(h, 0.0f);
                *(ushort*)(sH + rowl * 256 + (((colg >> 3) ^ (rowl & 15)) << 4) + (colg & 7) * 2) = f2b(h);
            }
        }
    }
    __syncthreads();

    // ---- score pass via MFMA: each wave owns 16 rows (wave*16 .. wave*16+15)
    // B fragments direct from L2-resident wtT/wsT (linear 16-B loads).
    {
        f32x4 at_[2], as_[2];
#pragma unroll
        for (int n = 0; n < 2; ++n) { at_[n] = 0; as_[n] = 0; }

#pragma unroll
        for (int kk = 0; kk < 4; ++kk) {
            bf16x8 aH, bT[2], bS[2];
            const int slot = kk * 4 + lq;
            const int ra = wave * 16 + lr;
            aH = *(const bf16x8*)(sH + ra * 256 + ((slot ^ (ra & 15)) << 4));
#pragma unroll
            for (int n = 0; n < 2; ++n) {
                const int f = n * 16 + lr;
                bT[n] = *(const bf16x8*)(wtT + f * 128 + kk * 32 + lq * 8);
                bS[n] = *(const bf16x8*)(wsT + f * 128 + kk * 32 + lq * 8);
            }
#pragma unroll
            for (int n = 0; n < 2; ++n) {
                at_[n] = __builtin_amdgcn_mfma_f32_16x16x32_bf16(aH, bT[n], at_[n], 0, 0, 0);
                as_[n] = __builtin_amdgcn_mfma_f32_16x16x32_bf16(aH, bS[n], as_[n], 0, 0, 0);
            }
        }

        // gated combine + row-reduce over 32 F-cols -> w = exp(a)
#pragma unroll
        for (int r = 0; r < 4; ++r) {
            float s = 0.f;
#pragma unroll
            for (int n = 0; n < 2; ++n) {
                const int f = n * 16 + lr;
                float tv = tanhf(at_[n][r] + sbt[f]);
                float sg = 1.0f / (1.0f + __expf(-(as_[n][r] + sbs[f])));
                s += tv * sg * sWa[f];
            }
            s += __shfl_xor(s, 1);
            s += __shfl_xor(s, 2);
            s += __shfl_xor(s, 4);
            s += __shfl_xor(s, 8);
            if (lr == 0)
                sw[wave * 16 + lq * 4 + r] = __expf(s + ba0);
        }
    }
    __syncthreads();

    // ---- per-bag partial reduce from LDS, atomically into Mraw/den.
    // 512 threads: d = t&127, quarter = t>>7 covers rows [q*32, q*32+32).
    {
        const int d = t & 127, q = t >> 7;
        const int r0 = q * 32;
        float accv = 0.f, accw = 0.f;
        int curbag = sbag[r0];
        for (int r = 0; r < 32; ++r) {
            const int rr = r0 + r;
            const int bg = sbag[rr];
            if (bg != curbag) {
                atomicAdd(&Mraw[curbag * 128 + d], accv);
                if (d == 0) atomicAdd(&dden[curbag], accw);
                accv = 0.f; accw = 0.f; curbag = bg;
            }
            const float w = sw[rr];
            const ushort hv = *(const ushort*)(sH + rr * 256 + ((((d >> 3) ^ (rr & 15))) << 4) + (d & 7) * 2);
            accv += w * b2f(hv);
            accw += w;
        }
        atomicAdd(&Mraw[curbag * 128 + d], accv);
        if (d == 0) atomicAdd(&dden[curbag], accw);
    }
}

// ---------------------------------------------------------------------------
// K2: finalize — M = Mraw/den, projector + L2 normalize. One block per bag.
// ---------------------------------------------------------------------------
__global__ __launch_bounds__(128) void k_final(
    const float* __restrict__ Mraw, const float* __restrict__ dden,
    const float* __restrict__ Wp, const float* __restrict__ bp,
    float* __restrict__ out)
{
    __shared__ float sM[128];
    const int b = blockIdx.x, t = threadIdx.x;
    const float den = dden[b];
    const float inv_den = den > 0.f ? 1.0f / den : 0.0f;

    float m = Mraw[b * 128 + t] * inv_den;
    sM[t] = m;
    out[b * 128 + t] = m;
    __syncthreads();

    if (t < 32) {
        float p = bp[t];
        for (int d = 0; d < 128; ++d) p += sM[d] * Wp[d * 32 + t];
        float ss = p * p;
#pragma unroll
        for (int mm = 1; mm < 32; mm <<= 1) ss += __shfl_xor(ss, mm);
        float nrm = sqrtf(ss);
        out[32768 + b * 32 + t] = p / fmaxf(nrm, 1e-12f);
    }
}

// ---------------------------------------------------------------------------
extern "C" void kernel_launch(void* const* d_in, const int* in_sizes, int n_in,
                              void* d_out, int out_size, void* d_ws, size_t ws_size,
                              hipStream_t stream)
{
    const float* x  = (const float*)d_in[0];
    const int*   idxs = (const int*)d_in[1];
    const float* W1 = (const float*)d_in[2];
    const float* b1 = (const float*)d_in[3];
    const float* Wt = (const float*)d_in[4];
    const float* bt = (const float*)d_in[5];
    const float* Ws = (const float*)d_in[6];
    const float* bs = (const float*)d_in[7];
    const float* Wa = (const float*)d_in[8];
    const float* ba = (const float*)d_in[9];
    const float* Wp = (const float*)d_in[10];
    const float* bp = (const float*)d_in[11];
    float* out = (float*)d_out;

    // ws layout: Mraw f32 [256][128] 128 KB | den 1 KB | w1t2 bf16 256 KB | wtT 8 KB | wsT 8 KB
    char* ws = (char*)d_ws;
    float*  Mraw = (float*)ws;
    float*  dden = (float*)(ws + 131072);
    ushort* w1t2 = (ushort*)(ws + 132096);
    ushort* wtT  = (ushort*)(ws + 132096 + 262144);
    ushort* wsT  = (ushort*)(ws + 132096 + 262144 + 8192);

    k_prep<<<512, 256, 0, stream>>>(W1, Wt, Ws, w1t2, wtT, wsT, Mraw, dden);
    k_fused_gemm<<<2048, 512, 0, stream>>>(x, w1t2, wtT, wsT, b1, bt, bs, Wa, ba, idxs, Mraw, dden);
    k_final<<<NBAGS, 128, 0, stream>>>(Mraw, dden, Wp, bp, out);
}

// Round 10
// 229.332 us; speedup vs baseline: 1.1317x; 1.1317x over previous
//
#include <hip/hip_runtime.h>
#include <hip/hip_bf16.h>

// Problem constants
#define NTOT 262144
#define LDIM 1024
#define DDIM 128
#define FDIM 32
#define NBAGS 256

typedef __attribute__((ext_vector_type(8))) short bf16x8;
typedef __attribute__((ext_vector_type(4))) float f32x4;

__device__ __forceinline__ unsigned short f2b(float f) {
    __hip_bfloat16 h = __float2bfloat16(f);   // RNE
    return __builtin_bit_cast(unsigned short, h);
}
__device__ __forceinline__ float b2f(unsigned short u) {
    union { float f; unsigned int i; } c;
    c.i = ((unsigned int)u) << 16;
    return c.f;
}

// ---------------------------------------------------------------------------
// K0: (a) W1 [1024][128] fp32 -> w1t2: kt-tiled, PRE-SWIZZLED bf16 layout:
//     element (col,k): kt=k>>6, ko=k&63, cc=ko>>3, kr=ko&7 ->
//     w1t2[kt*8192 + col*64 + (cc^(col&7))*8 + kr]. GEMM stages with a pure
//     linear copy; the MFMA read-side XOR undoes the pre-swizzle.
//     (b) Wt/Ws -> wtT/wsT [32][128] bf16.  (c) zero Mraw/dden.
// ---------------------------------------------------------------------------
__global__ void k_prep(const float* __restrict__ W1, const float* __restrict__ Wt,
                       const float* __restrict__ Ws,
                       ushort* __restrict__ w1t2, ushort* __restrict__ wtT,
                       ushort* __restrict__ wsT,
                       float* __restrict__ Mraw, float* __restrict__ dden) {
    int gid = blockIdx.x * 256 + threadIdx.x;          // 512*256 = 131072 threads
    if (gid < LDIM * DDIM) {
        int col = gid & 127, k = gid >> 7;             // W1 row-major: gid = k*128+col
        int kt = k >> 6, ko = k & 63;
        int cc = ko >> 3, kr = ko & 7;
        w1t2[kt * 8192 + col * 64 + (cc ^ (col & 7)) * 8 + kr] = f2b(W1[gid]);
    }
    if (gid < DDIM * FDIM) {                           // 4096
        int f = gid & 31, d = gid >> 5;                // Wt row-major: gid = d*32+f
        wtT[f * 128 + d] = f2b(Wt[gid]);
        wsT[f * 128 + d] = f2b(Ws[gid]);
    }
    if (gid < NBAGS * DDIM) Mraw[gid] = 0.0f;
    if (gid < NBAGS) dden[gid] = 0.0f;
}

// ---------------------------------------------------------------------------
// K1: H = relu(x@W1+b1) (stays in LDS); a = (tanh(HWt+bt)*sigmoid(HWs+bs))@Wa+ba
// w = exp(a) (|a| <= ~5.7, no max needed); per-bag partials into Mraw/den.
// 512 threads, 128x128 tile, BK=64, 8 waves (4x2), wave tile 32x64.
// TWO-DEEP register prefetch + RAW barriers (T4 counted-vmcnt):
//   b1(raw) -> stage(kt) [loads issued kt-2; compiler emits counted vmcnt]
//   -> lgkmcnt(0)+b2(raw) -> issue(kt+2) -> MFMA(kt)
// __syncthreads would force vmcnt(0) at every barrier, collapsing the
// prefetch window to one phase; raw s_barrier keeps ~2 iterations in flight.
// Safety: loads target private VGPRs (no cross-wave hazard at b1); ds_writes
// covered by explicit lgkmcnt(0) before b2; each wave's ds_reads are consumed
// (compiler lgkm waits before MFMA use) before it reaches b1.
// ---------------------------------------------------------------------------
__global__ __launch_bounds__(512, 4) void k_fused_gemm(
    const float* __restrict__ x, const ushort* __restrict__ w1t2,
    const ushort* __restrict__ wtT, const ushort* __restrict__ wsT,
    const float* __restrict__ b1,
    const float* __restrict__ bt, const float* __restrict__ bs,
    const float* __restrict__ Wa, const float* __restrict__ ba,
    const int* __restrict__ idxs,
    float* __restrict__ Mraw, float* __restrict__ dden)
{
    __shared__ __align__(16) ushort sAB[16384];    // 32 KB: A tile | B tile, later sH
    __shared__ float sb1[128];
    __shared__ float sbt[32], sbs[32], sWa[32];
    __shared__ float sw[128];                      // per-row softmax weight
    __shared__ int   sbag[128];                    // per-row bag id

    const int t    = threadIdx.x;
    const int lane = t & 63;
    const int wave = t >> 6;                       // 0..7
    const int wr   = wave >> 1, wc = wave & 1;     // wave tile: rows wr*32, cols wc*64
    const int lq   = lane >> 4, lr = lane & 15;
    const int row0 = blockIdx.x * 128;

    if (t < 128) { sb1[t] = b1[t]; sbag[t] = idxs[row0 + t]; }
    if (t < 32)  { sbt[t] = bt[t]; sbs[t] = bs[t]; sWa[t] = Wa[t]; }
    const float ba0 = ba[0];

    f32x4 acc[2][4];
#pragma unroll
    for (int m = 0; m < 2; ++m)
#pragma unroll
        for (int n = 0; n < 4; ++n) acc[m][n] = 0;

    char* sA = (char*)sAB;
    char* sB = (char*)sAB + 16384;

    // ---- staging geometry ----
    // A: j=0..3, row = (t>>4) + 32j, colchunk = t&15 (16B of fp32)
    const int arow  = t >> 4;                  // 0..31
    const int acol4 = (t & 15) * 4;            // fp32 col 0..60
    const float* xb = x + (size_t)(row0 + arow) * LDIM + acol4;
    const int a_base = (((acol4 >> 3) ^ (arow & 7)) << 4) + (acol4 & 7) * 2;
    // B: linear copy, chunk c = t + 512*jj -> 16 B at sB + c*16
    const ushort* bb = w1t2 + t * 8;

    // prologue: issue loads for kt=0 (slot 0) and kt=1 (slot 1)
    float4 av[2][4];
    bf16x8 bv[2][2];
#pragma unroll
    for (int j = 0; j < 4; ++j) av[0][j] = *(const float4*)(xb + j * (32 * LDIM));
#pragma unroll
    for (int jj = 0; jj < 2; ++jj) bv[0][jj] = *(const bf16x8*)(bb + jj * 4096);
#pragma unroll
    for (int j = 0; j < 4; ++j) av[1][j] = *(const float4*)(xb + 64 + j * (32 * LDIM));
#pragma unroll
    for (int jj = 0; jj < 2; ++jj) bv[1][jj] = *(const bf16x8*)(bb + 8192 + jj * 4096);

    for (int kt = 0; kt < 16; ++kt) {
        const int p = kt & 1;

        __builtin_amdgcn_s_barrier();              // b1: raw, NO vmcnt drain
        __builtin_amdgcn_sched_barrier(0);

        // stage registers (issued at kt-2) -> LDS
        // (compiler inserts the counted vmcnt wait for av[p]/bv[p] use)
#pragma unroll
        for (int j = 0; j < 4; ++j) {
            float4 f = av[p][j];
            uint2 pk;
            pk.x = (unsigned)f2b(f.x) | ((unsigned)f2b(f.y) << 16);
            pk.y = (unsigned)f2b(f.z) | ((unsigned)f2b(f.w) << 16);
            *(uint2*)(sA + (arow + 32 * j) * 128 + a_base) = pk;
        }
#pragma unroll
        for (int jj = 0; jj < 2; ++jj)
            *(bf16x8*)(sB + t * 16 + jj * 8192) = bv[p][jj];

        asm volatile("s_waitcnt lgkmcnt(0)" ::: "memory");   // ds_writes visible
        __builtin_amdgcn_sched_barrier(0);
        __builtin_amdgcn_s_barrier();              // b2: raw, staging published
        __builtin_amdgcn_sched_barrier(0);

        // issue loads for kt+2 into the register slot just freed
        if (kt < 14) {
            const float* xk = xb + (kt + 2) * 64;
#pragma unroll
            for (int j = 0; j < 4; ++j) av[p][j] = *(const float4*)(xk + j * (32 * LDIM));
            const ushort* bk = bb + (kt + 2) * 8192;
#pragma unroll
            for (int jj = 0; jj < 2; ++jj) bv[p][jj] = *(const bf16x8*)(bk + jj * 4096);
        }

#pragma unroll
        for (int kk = 0; kk < 2; ++kk) {
            bf16x8 aF[2], bF[4];
#pragma unroll
            for (int m = 0; m < 2; ++m) {
                int ra = wr * 32 + m * 16 + lr;    // A: row = lane%16
                aF[m] = *(const bf16x8*)(sA + ra * 128 + (((kk * 4 + lq) ^ (ra & 7)) << 4));
            }
#pragma unroll
            for (int n = 0; n < 4; ++n) {
                int cb = wc * 64 + n * 16 + lr;    // B: col = lane%16
                bF[n] = *(const bf16x8*)(sB + cb * 128 + (((kk * 4 + lq) ^ (cb & 7)) << 4));
            }
#pragma unroll
            for (int m = 0; m < 2; ++m)
#pragma unroll
                for (int n = 0; n < 4; ++n)
                    acc[m][n] = __builtin_amdgcn_mfma_f32_16x16x32_bf16(aF[m], bF[n], acc[m][n], 0, 0, 0);
        }
    }
    __syncthreads();   // full drain once; K-loop LDS dead; reuse 32 KB as sH

    // epilogue: bias + relu, bf16, into swizzled sH [128 rows][256 B], slot ^= row&15
    char* sH = (char*)sAB;
#pragma unroll
    for (int m = 0; m < 2; ++m) {
#pragma unroll
        for (int n = 0; n < 4; ++n) {
            const int colg = wc * 64 + n * 16 + lr;          // C/D: col = lane&15
            const float bias = sb1[colg];
#pragma unroll
            for (int r = 0; r < 4; ++r) {
                const int rowl = wr * 32 + m * 16 + lq * 4 + r; // C/D: row = (lane>>4)*4+reg
                float h = acc[m][n][r] + bias;
                h = fmaxf(h, 0.0f);
                *(ushort*)(sH + rowl * 256 + (((colg >> 3) ^ (rowl & 15)) << 4) + (colg & 7) * 2) = f2b(h);
            }
        }
    }
    __syncthreads();

    // ---- score pass via MFMA: each wave owns 16 rows (wave*16 .. wave*16+15)
    // B fragments direct from L2-resident wtT/wsT (linear 16-B loads).
    {
        f32x4 at_[2], as_[2];
#pragma unroll
        for (int n = 0; n < 2; ++n) { at_[n] = 0; as_[n] = 0; }

#pragma unroll
        for (int kk = 0; kk < 4; ++kk) {
            bf16x8 aH, bT[2], bS[2];
            const int slot = kk * 4 + lq;
            const int ra = wave * 16 + lr;
            aH = *(const bf16x8*)(sH + ra * 256 + ((slot ^ (ra & 15)) << 4));
#pragma unroll
            for (int n = 0; n < 2; ++n) {
                const int f = n * 16 + lr;
                bT[n] = *(const bf16x8*)(wtT + f * 128 + kk * 32 + lq * 8);
                bS[n] = *(const bf16x8*)(wsT + f * 128 + kk * 32 + lq * 8);
            }
#pragma unroll
            for (int n = 0; n < 2; ++n) {
                at_[n] = __builtin_amdgcn_mfma_f32_16x16x32_bf16(aH, bT[n], at_[n], 0, 0, 0);
                as_[n] = __builtin_amdgcn_mfma_f32_16x16x32_bf16(aH, bS[n], as_[n], 0, 0, 0);
            }
        }

        // gated combine + row-reduce over 32 F-cols -> w = exp(a)
#pragma unroll
        for (int r = 0; r < 4; ++r) {
            float s = 0.f;
#pragma unroll
            for (int n = 0; n < 2; ++n) {
                const int f = n * 16 + lr;
                float tv = tanhf(at_[n][r] + sbt[f]);
                float sg = 1.0f / (1.0f + __expf(-(as_[n][r] + sbs[f])));
                s += tv * sg * sWa[f];
            }
            s += __shfl_xor(s, 1);
            s += __shfl_xor(s, 2);
            s += __shfl_xor(s, 4);
            s += __shfl_xor(s, 8);
            if (lr == 0)
                sw[wave * 16 + lq * 4 + r] = __expf(s + ba0);
        }
    }
    __syncthreads();

    // ---- per-bag partial reduce from LDS, atomically into Mraw/den.
    // 512 threads: d = t&127, quarter = t>>7 covers rows [q*32, q*32+32).
    {
        const int d = t & 127, q = t >> 7;
        const int r0 = q * 32;
        float accv = 0.f, accw = 0.f;
        int curbag = sbag[r0];
        for (int r = 0; r < 32; ++r) {
            const int rr = r0 + r;
            const int bg = sbag[rr];
            if (bg != curbag) {
                atomicAdd(&Mraw[curbag * 128 + d], accv);
                if (d == 0) atomicAdd(&dden[curbag], accw);
                accv = 0.f; accw = 0.f; curbag = bg;
            }
            const float w = sw[rr];
            const ushort hv = *(const ushort*)(sH + rr * 256 + ((((d >> 3) ^ (rr & 15))) << 4) + (d & 7) * 2);
            accv += w * b2f(hv);
            accw += w;
        }
        atomicAdd(&Mraw[curbag * 128 + d], accv);
        if (d == 0) atomicAdd(&dden[curbag], accw);
    }
}

// ---------------------------------------------------------------------------
// K2: finalize — M = Mraw/den, projector + L2 normalize. One block per bag.
// ---------------------------------------------------------------------------
__global__ __launch_bounds__(128) void k_final(
    const float* __restrict__ Mraw, const float* __restrict__ dden,
    const float* __restrict__ Wp, const float* __restrict__ bp,
    float* __restrict__ out)
{
    __shared__ float sM[128];
    const int b = blockIdx.x, t = threadIdx.x;
    const float den = dden[b];
    const float inv_den = den > 0.f ? 1.0f / den : 0.0f;

    float m = Mraw[b * 128 + t] * inv_den;
    sM[t] = m;
    out[b * 128 + t] = m;
    __syncthreads();

    if (t < 32) {
        float p = bp[t];
        for (int d = 0; d < 128; ++d) p += sM[d] * Wp[d * 32 + t];
        float ss = p * p;
#pragma unroll
        for (int mm = 1; mm < 32; mm <<= 1) ss += __shfl_xor(ss, mm);
        float nrm = sqrtf(ss);
        out[32768 + b * 32 + t] = p / fmaxf(nrm, 1e-12f);
    }
}

// ---------------------------------------------------------------------------
extern "C" void kernel_launch(void* const* d_in, const int* in_sizes, int n_in,
                              void* d_out, int out_size, void* d_ws, size_t ws_size,
                              hipStream_t stream)
{
    const float* x  = (const float*)d_in[0];
    const int*   idxs = (const int*)d_in[1];
    const float* W1 = (const float*)d_in[2];
    const float* b1 = (const float*)d_in[3];
    const float* Wt = (const float*)d_in[4];
    const float* bt = (const float*)d_in[5];
    const float* Ws = (const float*)d_in[6];
    const float* bs = (const float*)d_in[7];
    const float* Wa = (const float*)d_in[8];
    const float* ba = (const float*)d_in[9];
    const float* Wp = (const float*)d_in[10];
    const float* bp = (const float*)d_in[11];
    float* out = (float*)d_out;

    // ws layout: Mraw f32 [256][128] 128 KB | den 1 KB | w1t2 bf16 256 KB | wtT 8 KB | wsT 8 KB
    char* ws = (char*)d_ws;
    float*  Mraw = (float*)ws;
    float*  dden = (float*)(ws + 131072);
    ushort* w1t2 = (ushort*)(ws + 132096);
    ushort* wtT  = (ushort*)(ws + 132096 + 262144);
    ushort* wsT  = (ushort*)(ws + 132096 + 262144 + 8192);

    k_prep<<<512, 256, 0, stream>>>(W1, Wt, Ws, w1t2, wtT, wsT, Mraw, dden);
    k_fused_gemm<<<2048, 512, 0, stream>>>(x, w1t2, wtT, wsT, b1, bt, bs, Wa, ba, idxs, Mraw, dden);
    k_final<<<NBAGS, 128, 0, stream>>>(Mraw, dden, Wp, bp, out);
}